// Round 9
// baseline (446.359 us; speedup 1.0000x reference)
//
#include <hip/hip_runtime.h>

// Fused Bahdanau context-attention pooling, MI355X (gfx950).
// R9: kill the dominant VMEM stream (Wk re-reads) by staging Wk ONCE per CU
// into 128KB of swizzled LDS; waves then run independent 16-row tiles with
// A direct from global (software-pipelined batches) and B from LDS.
//   K1 prep     : q = query@Wq^T (f32), Wk -> bf16 in ws, mask-layout flag
//   K2 main     : 512 blocks x 512 thr (1/CU, 2 rounds). Block: stage wkb
//                 (bf16 128KB) -> XOR-swizzled LDS, one barrier. Then each
//                 of 8 waves: 2 independent 16-row tiles: A-frags f32->bf16
//                 from global (2-deep batch pipeline), B ds_read_b128 from
//                 LDS, mfma 16x16x32 (acc[8], full 128 cols), in-wave
//                 score/softmax, e broadcast via 16 static shuffles,
//                 ctx partial re-read from L2-hot global. No LDS after
//                 stage, no barriers after stage.
//   K3 combineA : per b: global M, D over 256 chunk (m,d); scl[j]
//   K4 combineB : context = sum_j scl_j*ctxp_j ; weights = exp(score-M)/D

typedef __attribute__((ext_vector_type(8))) short short8;
typedef __attribute__((ext_vector_type(4))) float f32x4;

#define S_LEN 4096
#define BATCH 32
#define KVD 512
#define AD 128
#define CHN 16                           // rows per tile
#define GRPS_PER_B (S_LEN / CHN)         // 256
#define NTILE (BATCH * GRPS_PER_B)       // 8192
#define NBLK_MAIN 512
#define TPB (NTILE / NBLK_MAIN)          // 16 tiles per block
#define TPW (TPB / 8)                    // 2 tiles per wave

// ws byte offsets (ws ~1 GB per harness poison-fill size)
#define FLAG_OFF   0
#define Q_OFF      1024
#define WK_OFF     17408        // + 128*512*2  = 131072 -> 148480
#define SCORES_OFF 148480       // + 32*4096*4  = 524288 -> 672768
#define MD_OFF     672768       // + 8192*2*4   = 65536  -> 738304
#define CTXP_OFF   738304       // + 8192*512*4 = 16777216 -> 17515520
#define SCL_OFF    17515520     // + 32*256*4   = 32768  -> 17548288
#define MD2_OFF    17548288     // + 32*2*4

__device__ __forceinline__ unsigned short f2bf_rne(float f) {
  unsigned int u = __float_as_uint(f);
  u = (u + 0x7FFFu + ((u >> 16) & 1u)) >> 16;
  return (unsigned short)u;
}
// round-half-up pack of 2 f32 -> 1 dword of 2 bf16 (lo, hi)
__device__ __forceinline__ unsigned int packbf(float a, float b) {
  unsigned int lo = __float_as_uint(a) + 0x8000u;
  unsigned int hi = __float_as_uint(b) + 0x8000u;
  return (lo >> 16) | (hi & 0xFFFF0000u);
}
__device__ __forceinline__ float tanh_fast(float x) {
  return 1.0f - 2.0f / (1.0f + __expf(2.0f * x));
}

__global__ __launch_bounds__(256) void prep_kernel(
    const float* __restrict__ query, const float* __restrict__ Wq,
    const float* __restrict__ Wk, const void* __restrict__ maskp,
    float* __restrict__ qws, unsigned short* __restrict__ wkb,
    int* __restrict__ flagp) {
  int blk = blockIdx.x, t = threadIdx.x;
  if (blk < 32) {
    __shared__ float qrow[KVD];
    qrow[t] = query[blk * KVD + t];
    qrow[t + 256] = query[blk * KVD + t + 256];
    __syncthreads();
    int a = t >> 1, half = t & 1;
    const float4* wq4 = (const float4*)(Wq + (size_t)a * KVD + half * 256);
    const float4* qr4 = (const float4*)(qrow + half * 256);
    float s = 0.f;
#pragma unroll 8
    for (int i = 0; i < 64; ++i) {
      float4 wv = wq4[i], qv = qr4[i];
      s += wv.x * qv.x + wv.y * qv.y + wv.z * qv.z + wv.w * qv.w;
    }
    s += __shfl_xor(s, 1);
    if (half == 0) qws[blk * AD + a] = s;
  } else if (blk < 40) {
    int j = blk - 32;
    const float4* src = (const float4*)Wk;
#pragma unroll 4
    for (int i = 0; i < 8; ++i) {
      int idx4 = j * 2048 + i * 256 + t;
      float4 v = src[idx4];
      ushort4 o;
      o.x = f2bf_rne(v.x); o.y = f2bf_rne(v.y);
      o.z = f2bf_rne(v.z); o.w = f2bf_rne(v.w);
      ((ushort4*)wkb)[idx4] = o;
    }
  } else {
    __shared__ int okv;
    if (t == 0) okv = 1;
    __syncthreads();
    if (t < 128) {
      int wv = ((const int*)maskp)[t];
      if (!(wv == 0 || wv == 1)) okv = 0;
    }
    __syncthreads();
    if (t == 0) flagp[0] = okv;  // 1 = int32 layout, 0 = byte layout
  }
}

__global__ __launch_bounds__(512, 1) void main_kernel(
    const float* __restrict__ kv, const void* __restrict__ maskp,
    const float* __restrict__ Ws, const float* __restrict__ qws,
    const unsigned short* __restrict__ wkb, const int* __restrict__ flagp,
    float* __restrict__ scores, float* __restrict__ md,
    float* __restrict__ ctxp) {
  int t = threadIdx.x;
  int lane = t & 63, wave = t >> 6;
  int blk = blockIdx.x;
  int b = blk / (NBLK_MAIN / BATCH);       // 16 blocks per b
  int lr = lane & 15, lg = lane >> 4;

  __shared__ __align__(16) char bshare[AD * KVD * 2];  // 128KB swizzled Wk bf16

  // ---- stage Wk bf16 -> swizzled LDS (once per block) ----
  // unit i = 16B; row = (i*16)>>10; dst byte = (i*16) ^ ((row&7)<<4)
  {
    const uint4* wk4 = (const uint4*)wkb;
#pragma unroll
    for (int i = t; i < AD * KVD * 2 / 16; i += 512) {
      uint4 v = wk4[i];
      int byte = i << 4;
      int dst = byte ^ (((byte >> 10) & 7) << 4);
      *(uint4*)(bshare + dst) = v;
    }
  }

  // per-b constants (b constant within block: 16 tiles = within one b)
  int flag = flagp[0];
  float qv[8], wv[8];
#pragma unroll
  for (int n = 0; n < 8; ++n) {
    qv[n] = qws[b * AD + n * 16 + lr];
    wv[n] = Ws[n * 16 + lr];
  }
  __syncthreads();  // Wk staged; waves independent from here on

  for (int it = 0; it < TPW; ++it) {
    int g = blk * TPB + wave * TPW + it;  // global 16-row tile id
    int s0 = (g & 255) * CHN;             // first row within b

    // mask for this tile
    int mload = 0;
    if (lane < CHN) {
      int gs = b * S_LEN + s0 + lane;
      mload = flag ? ((const int*)maskp)[gs]
                   : (int)((const unsigned char*)maskp)[gs];
    }

    // ---- projection: A direct from global (2-deep batch), B from LDS ----
    const float* arow = kv + ((size_t)b * S_LEN + s0 + lr) * KVD + lg * 8;
    f32x4 acc[8];
#pragma unroll
    for (int n = 0; n < 8; ++n) acc[n] = (f32x4)0.f;

    float4 vc[8], vn[8];
    // prime batch 0 (kk = 0..3)
#pragma unroll
    for (int j = 0; j < 8; ++j)
      vn[j] = *(const float4*)(arow + (j >> 1) * 32 + (j & 1) * 4);

#pragma unroll
    for (int bb = 0; bb < 4; ++bb) {
#pragma unroll
      for (int j = 0; j < 8; ++j) vc[j] = vn[j];
      if (bb < 3) {
#pragma unroll
        for (int j = 0; j < 8; ++j)
          vn[j] = *(const float4*)(arow + ((bb + 1) * 4 + (j >> 1)) * 32 + (j & 1) * 4);
      }
#pragma unroll
      for (int k2 = 0; k2 < 4; ++k2) {
        int kk = bb * 4 + k2;
        short8 af;
        ((unsigned int*)&af)[0] = packbf(vc[2 * k2].x, vc[2 * k2].y);
        ((unsigned int*)&af)[1] = packbf(vc[2 * k2].z, vc[2 * k2].w);
        ((unsigned int*)&af)[2] = packbf(vc[2 * k2 + 1].x, vc[2 * k2 + 1].y);
        ((unsigned int*)&af)[3] = packbf(vc[2 * k2 + 1].z, vc[2 * k2 + 1].w);
#pragma unroll
        for (int n = 0; n < 8; ++n) {
          int bbyte = (((16 * n + lr) << 10) + (kk << 6) + (lg << 4)) ^ ((lr & 7) << 4);
          short8 bf = *(const short8*)(bshare + bbyte);
          acc[n] = __builtin_amdgcn_mfma_f32_16x16x32_bf16(af, bf, acc[n], 0, 0, 0);
        }
      }
    }

    // ---- scores: D layout col a = 16n+lr, row s = 4lg+reg ----
    float sc[4];
#pragma unroll
    for (int reg = 0; reg < 4; ++reg) {
      float v = 0.f;
#pragma unroll
      for (int n = 0; n < 8; ++n)
        v += tanh_fast(qv[n] + acc[n][reg]) * wv[n];
      v += __shfl_xor(v, 1);
      v += __shfl_xor(v, 2);
      v += __shfl_xor(v, 4);
      v += __shfl_xor(v, 8);
      int row = 4 * lg + reg;
      int mk = __shfl(mload, row);
      sc[reg] = mk ? v : -INFINITY;
    }

    // ---- in-wave softmax over 16 rows ----
    float m = fmaxf(fmaxf(sc[0], sc[1]), fmaxf(sc[2], sc[3]));
    m = fmaxf(m, __shfl_xor(m, 16));
    m = fmaxf(m, __shfl_xor(m, 32));
    float e[4], d = 0.f;
#pragma unroll
    for (int reg = 0; reg < 4; ++reg) {
      e[reg] = (sc[reg] == -INFINITY) ? 0.f : __expf(sc[reg] - m);
      d += e[reg];
    }
    d += __shfl_xor(d, 16);
    d += __shfl_xor(d, 32);

    if (lr == 0) {
#pragma unroll
      for (int reg = 0; reg < 4; ++reg)
        scores[b * S_LEN + s0 + 4 * lg + reg] = sc[reg];
    }
    if (lane == 0) {
      md[g * 2] = (d > 0.f) ? m : -INFINITY;
      md[g * 2 + 1] = d;
    }

    // ---- broadcast e to all rows via static shuffles (no LDS) ----
    // row 4j+reg lives in e[reg] of lanes with lg == j
    float e_all[16];
#pragma unroll
    for (int j = 0; j < 4; ++j) {
      e_all[4 * j + 0] = __shfl(e[0], 16 * j);
      e_all[4 * j + 1] = __shfl(e[1], 16 * j);
      e_all[4 * j + 2] = __shfl(e[2], 16 * j);
      e_all[4 * j + 3] = __shfl(e[3], 16 * j);
    }

    // ---- ctx partial: re-read own tile from L2, c = lane*8..+7 ----
    float4 c0 = make_float4(0.f, 0.f, 0.f, 0.f);
    float4 c1 = make_float4(0.f, 0.f, 0.f, 0.f);
    const float* kvc = kv + ((size_t)b * S_LEN + s0) * KVD + lane * 8;
#pragma unroll
    for (int s = 0; s < CHN; ++s) {
      float ev = e_all[s];
      float4 v0 = *(const float4*)(kvc + (size_t)s * KVD);
      float4 v1 = *(const float4*)(kvc + (size_t)s * KVD + 4);
      c0.x += ev * v0.x; c0.y += ev * v0.y; c0.z += ev * v0.z; c0.w += ev * v0.w;
      c1.x += ev * v1.x; c1.y += ev * v1.y; c1.z += ev * v1.z; c1.w += ev * v1.w;
    }
    float* cp = ctxp + (size_t)g * KVD + lane * 8;
    *(float4*)cp = c0;
    *(float4*)(cp + 4) = c1;
  }
}

__global__ __launch_bounds__(256) void combineA_kernel(
    const float* __restrict__ md, float* __restrict__ scl,
    float* __restrict__ md2) {
  int b = blockIdx.x, t = threadIdx.x;  // 256 threads = 4 waves, 256 groups
  float mv = md[(b * GRPS_PER_B + t) * 2];
  float dv = md[(b * GRPS_PER_B + t) * 2 + 1];
  __shared__ float rmax[4], rsum[4];
  float m = mv;
  m = fmaxf(m, __shfl_xor(m, 1));
  m = fmaxf(m, __shfl_xor(m, 2));
  m = fmaxf(m, __shfl_xor(m, 4));
  m = fmaxf(m, __shfl_xor(m, 8));
  m = fmaxf(m, __shfl_xor(m, 16));
  m = fmaxf(m, __shfl_xor(m, 32));
  if ((t & 63) == 0) rmax[t >> 6] = m;
  __syncthreads();
  float M = fmaxf(fmaxf(rmax[0], rmax[1]), fmaxf(rmax[2], rmax[3]));
  float e = (dv > 0.f) ? __expf(mv - M) : 0.f;
  float pd = e * dv;
  pd += __shfl_xor(pd, 1);
  pd += __shfl_xor(pd, 2);
  pd += __shfl_xor(pd, 4);
  pd += __shfl_xor(pd, 8);
  pd += __shfl_xor(pd, 16);
  pd += __shfl_xor(pd, 32);
  if ((t & 63) == 0) rsum[t >> 6] = pd;
  __syncthreads();
  float D = rsum[0] + rsum[1] + rsum[2] + rsum[3];
  float invD = 1.f / D;
  scl[b * GRPS_PER_B + t] = e * invD;
  if (t == 0) { md2[b * 2] = M; md2[b * 2 + 1] = invD; }
}

__global__ __launch_bounds__(256) void combineB_kernel(
    const float* __restrict__ scl, const float* __restrict__ md2,
    const float* __restrict__ ctxp, const float* __restrict__ scores,
    float* __restrict__ out) {
  int strip = blockIdx.x, b = blockIdx.y, t = threadIdx.x;
  if (strip < 8) {
    __shared__ float part[4][64];
    int c = strip * 64 + (t & 63);
    int jg = t >> 6;
    float sum = 0.f;
    for (int j = jg; j < GRPS_PER_B; j += 4)
      sum += scl[b * GRPS_PER_B + j] *
             ctxp[(size_t)(b * GRPS_PER_B + j) * KVD + c];
    part[jg][t & 63] = sum;
    __syncthreads();
    if (t < 64)
      out[b * KVD + c] = part[0][t] + part[1][t] + part[2][t] + part[3][t];
  } else {
    float M = md2[b * 2], invD = md2[b * 2 + 1];
    int sbase = (strip - 8) * 1024;
#pragma unroll
    for (int i = 0; i < 4; ++i) {
      int s = sbase + i * 256 + t;
      float scv = scores[b * S_LEN + s];
      out[BATCH * KVD + b * S_LEN + s] = __expf(scv - M) * invD;  // -inf -> 0
    }
  }
}

extern "C" void kernel_launch(void* const* d_in, const int* in_sizes, int n_in,
                              void* d_out, int out_size, void* d_ws, size_t ws_size,
                              hipStream_t stream) {
  const float* query = (const float*)d_in[0];
  const float* kv    = (const float*)d_in[1];
  const void*  maskp = d_in[2];
  const float* Wq    = (const float*)d_in[3];
  const float* Wk    = (const float*)d_in[4];
  const float* Ws    = (const float*)d_in[5];
  float* out = (float*)d_out;
  char* w = (char*)d_ws;
  int* flagp = (int*)(w + FLAG_OFF);
  float* qws = (float*)(w + Q_OFF);
  unsigned short* wkb = (unsigned short*)(w + WK_OFF);
  float* scores = (float*)(w + SCORES_OFF);
  float* md = (float*)(w + MD_OFF);
  float* ctxp = (float*)(w + CTXP_OFF);
  float* scl = (float*)(w + SCL_OFF);
  float* md2 = (float*)(w + MD2_OFF);

  prep_kernel<<<41, 256, 0, stream>>>(query, Wq, Wk, maskp, qws, wkb, flagp);
  main_kernel<<<NBLK_MAIN, 512, 0, stream>>>(kv, maskp, Ws, qws, wkb, flagp,
                                             scores, md, ctxp);
  combineA_kernel<<<BATCH, 256, 0, stream>>>(md, scl, md2);
  combineB_kernel<<<dim3(12, BATCH), 256, 0, stream>>>(scl, md2, ctxp, scores, out);
}